// Round 4
// baseline (492.610 us; speedup 1.0000x reference)
//
#include <hip/hip_runtime.h>

#define TT 1024
#define NN 256
#define CC 128
#define SS 128
#define DD 16            // LDS ring depth (rows of 128 floats)
#define NEG (-1e30f)
#define LOG2E 1.4426950408889634f
#define LN2 0.6931471805599453f

// log-sum-exp in log2 domain, 2-arg: log2(2^a + 2^b)  -- bit-identical to
// rounds 2/3 (absmax 0.0); this round changes only data movement.
__device__ __forceinline__ float lae2(float a, float b) {
    float m = fmaxf(a, b);
    float mn = fminf(a, b);
    float s = 1.0f + __builtin_amdgcn_exp2f(mn - m);
    return m + __builtin_amdgcn_logf(s);   // v_log_f32 is log2
}
// 3-arg: log2(2^a + 2^b + 2^c)
__device__ __forceinline__ float lae3(float a, float b, float c) {
    float m = fmaxf(fmaxf(a, b), c);       // fuses to v_max3_f32
    float s = __builtin_amdgcn_exp2f(a - m) + __builtin_amdgcn_exp2f(b - m)
            + __builtin_amdgcn_exp2f(c - m);
    return m + __builtin_amdgcn_logf(s);
}

// async global->LDS DMA, 4B per lane: lane l writes lds_base[l] from gp[l].
#define GLLDS(gp, lp) __builtin_amdgcn_global_load_lds( \
    (const __attribute__((address_space(1))) void*)(gp), \
    (__attribute__((address_space(3))) void*)(lp), 4, 0, 0)

// One wave per sample. Lane i owns extended positions l=4i..4i+3 (a0..a3);
// lane 63 additionally l=256 (a4). Cross-lane dep: one shfl_up per step.
//
// ROUND-3 LESSON: regalloc spills a 48-float register prefetch pipeline
// (VGPR=36, latency-bound at 476 cy/step). Fix: stage rows via
// global_load_lds into a 16-slot LDS ring — in-flight data costs ZERO
// registers (tracked by vmcnt), plus a 1-step 3-register LDS->reg prefetch
// to hide ds_read latency. Counted vmcnt(30), never 0, in the main loop.
__global__ __launch_bounds__(64, 1) void ctc_alpha_kernel(
    const float* __restrict__ lp, const int* __restrict__ tgt,
    const int* __restrict__ ilen_p, const int* __restrict__ tlen_p,
    float* __restrict__ ws)
{
    __shared__ float buf[DD][CC];    // 8 KB staging ring
    __shared__ float alds[260];      // finale

    const int n = blockIdx.x;
    const int lane = threadIdx.x;
    const int ilen = ilen_p[n];      // in [512, 1024]
    const int tlen = tlen_p[n];      // in [64, 128]

    // time-invariant gather indices: ext[4i+1]=tgt[2i], ext[4i+3]=tgt[2i+1]
    const int te = tgt[n * SS + 2 * lane]     & (CC - 1);
    const int to = tgt[n * SS + 2 * lane + 1] & (CC - 1);
    const int tprev = __shfl_up(to, 1, 64);   // tgt[2i-1]
    const bool skip1 = (lane > 0) && (te != tprev);
    const bool skip3 = (to != te);

    const float* base = lp + (size_t)n * CC;        // row t: + t*NN*CC
    const size_t stride = (size_t)NN * CC;

    // prologue: DMA rows 0..DD-1 into the ring (2 issues per row)
    #pragma unroll
    for (int d = 0; d < DD; ++d) {
        const float* gp = base + (size_t)d * stride;
        GLLDS(gp + lane,      &buf[d][0]);
        GLLDS(gp + 64 + lane, &buf[d][64]);
    }
    asm volatile("s_waitcnt vmcnt(30)" ::: "memory");   // row 0 resident
    float rbA = buf[0][0], r1A = buf[0][te], r2A = buf[0][to];
    float rbB, r1B, r2B;

    // pre-state: one normal step from this produces the exact alpha0
    float a0 = (lane == 0) ? 0.0f : NEG;
    float a1 = NEG, a2 = NEG, a3 = NEG, a4 = NEG;

    // consume regs X (= row tt); prefetch row tt+1 into regs Y.
    // lgkmcnt(0): X's ds_reads landed -> slot tt&15 safe to overwrite.
    // vmcnt(30): rows outstanding = tt+1..tt+16 (32 issues); oldest 2
    // (row tt+1) retired -> its LDS slot is valid to read.
#define STEP(rbX, r1X, r2X, rbY, r1Y, r2Y, tt) { \
    asm volatile("s_waitcnt lgkmcnt(0)" ::: "memory"); \
    { int tn = (tt) + DD; tn = (tn < TT) ? tn : (TT - 1); \
      const float* gp = base + (size_t)tn * stride; \
      const int sw = (tt) & (DD - 1); \
      GLLDS(gp + lane,      &buf[sw][0]); \
      GLLDS(gp + 64 + lane, &buf[sw][64]); } \
    asm volatile("s_waitcnt vmcnt(30)" ::: "memory"); \
    { const int sl = ((tt) + 1) & (DD - 1); \
      rbY = buf[sl][0]; r1Y = buf[sl][te]; r2Y = buf[sl][to]; } \
    const float eb = rbX * LOG2E; \
    const float e1 = r1X * LOG2E; \
    const float e3 = r2X * LOG2E; \
    const float s3 = __shfl_up(a3, 1, 64); \
    const float p3 = (lane == 0) ? NEG : s3; \
    const float n0 = eb + lae2(a0, p3); \
    const float n1 = e1 + lae3(a1, a0, skip1 ? p3 : NEG); \
    const float n2 = eb + lae2(a2, a1); \
    const float n3 = e3 + lae3(a3, a2, skip3 ? a1 : NEG); \
    const float n4 = eb + lae2(a4, a3); \
    a0 = n0; a1 = n1; a2 = n2; a3 = n3; a4 = n4; }

    int t = 0;
    for (; t + 2 <= ilen; t += 2) {
        STEP(rbA, r1A, r2A, rbB, r1B, r2B, t)
        STEP(rbB, r1B, r2B, rbA, r1A, r2A, t + 1)
    }
    if (t < ilen) {   // odd tail: consume A (row t), no prefetch
        const float eb = rbA * LOG2E;
        const float e1 = r1A * LOG2E;
        const float e3 = r2A * LOG2E;
        const float s3 = __shfl_up(a3, 1, 64);
        const float p3 = (lane == 0) ? NEG : s3;
        const float n0 = eb + lae2(a0, p3);
        const float n1 = e1 + lae3(a1, a0, skip1 ? p3 : NEG);
        const float n2 = eb + lae2(a2, a1);
        const float n3 = e3 + lae3(a3, a2, skip3 ? a1 : NEG);
        const float n4 = eb + lae2(a4, a3);
        a0 = n0; a1 = n1; a2 = n2; a3 = n3; a4 = n4;
    }

    // finale: loss = -logaddexp(alpha[2*tl], alpha[2*tl-1]) / tl
    alds[4 * lane + 0] = a0;
    alds[4 * lane + 1] = a1;
    alds[4 * lane + 2] = a2;
    alds[4 * lane + 3] = a3;
    if (lane == 63) alds[256] = a4;
    __syncthreads();   // also drains vmcnt/lgkmcnt (compiler-inserted)
    if (lane == 0) {
        const int idx = 2 * tlen;
        const float r = lae2(alds[idx], alds[idx - 1]);  // log2 domain
        ws[n] = -(r * LN2) / (float)tlen;                // back to ln, /tl
    }
}

__global__ __launch_bounds__(64) void ctc_reduce_kernel(
    const float* __restrict__ ws, float* __restrict__ out)
{
    const int lane = threadIdx.x;
    float s = ws[lane] + ws[lane + 64] + ws[lane + 128] + ws[lane + 192];
    #pragma unroll
    for (int off = 32; off > 0; off >>= 1)
        s += __shfl_down(s, off, 64);
    if (lane == 0) out[0] = s * (1.0f / NN);
}

extern "C" void kernel_launch(void* const* d_in, const int* in_sizes, int n_in,
                              void* d_out, int out_size, void* d_ws, size_t ws_size,
                              hipStream_t stream) {
    const float* lp  = (const float*)d_in[0];   // (T, N, C) f32
    const int*   tgt = (const int*)d_in[1];     // (N, S) i32
    const int*   il  = (const int*)d_in[2];     // (N,) i32
    const int*   tl  = (const int*)d_in[3];     // (N,) i32
    float* out = (float*)d_out;
    float* ws  = (float*)d_ws;

    hipLaunchKernelGGL(ctc_alpha_kernel, dim3(NN), dim3(64), 0, stream,
                       lp, tgt, il, tl, ws);
    hipLaunchKernelGGL(ctc_reduce_kernel, dim3(1), dim3(64), 0, stream, ws, out);
}

// Round 6
// 250.411 us; speedup vs baseline: 1.9672x; 1.9672x over previous
//
#include <hip/hip_runtime.h>

#define TT 1024
#define NN 256
#define CC 128
#define SS 128
#define STRB 131072u                  // NN*CC*4 bytes per time-row
#define CAPB (1023u * STRB)           // last valid row offset
#define LOG2E 1.4426950408889634f
#define LN2 0.6931471805599453f

// log2(2^a + 2^b) for the tiny epilogue only
__device__ __forceinline__ float lae2(float a, float b) {
    float m = fmaxf(a, b);
    float mn = fminf(a, b);
    float s = 1.0f + __builtin_amdgcn_exp2f(mn - m);
    return m + __builtin_amdgcn_logf(s);   // v_log_f32 is log2
}

// One wave per sample. Lane i owns extended positions l=4i..4i+3 (b0..b3);
// b4 is l=4i+4 (only lane 63's, l=256, is ever read).
//
// ROUND 2-4 LESSONS: (a) compiler sinks plain prefetch loads next to uses
// (one exposed latency per step, 476 cy); (b) LDS-ring with two hard waits
// per step serializes worse (825 cy). FIX: asm volatile global_load (order
// preserved, cannot be sunk) + counted s_waitcnt vmcnt(45) that TIES the
// consumed values as "+v" operands (hard dataflow edge). Linear-domain
// probabilities, per-lane exact power-of-2 scale frame kk
// (stored = alpha_true * 2^kk), rescale every 8 steps.
// ROUND 5 LESSON: RESCALE scales stored by 2^(127-e8), so kk += 127-e8
// (sign was flipped -> frame conversion exploded -> inf -> NaN).
__global__ __launch_bounds__(64, 1) void ctc_alpha_kernel(
    const float* __restrict__ lp, const int* __restrict__ tgt,
    const int* __restrict__ ilen_p, const int* __restrict__ tlen_p,
    float* __restrict__ ws)
{
    __shared__ float alds[260];

    const int n = blockIdx.x;
    const int lane = threadIdx.x;
    const int ilen = ilen_p[n];      // [512, 1024]
    const int tlen = tlen_p[n];      // [64, 128]

    const int te = tgt[n * SS + 2 * lane]     & (CC - 1);  // ext[4i+1]
    const int to = tgt[n * SS + 2 * lane + 1] & (CC - 1);  // ext[4i+3]
    const int tprev = __shfl_up(to, 1, 64);
    const bool skip1 = (lane > 0) && (te != tprev);
    const bool skip3 = (to != te);
    const unsigned te4 = (unsigned)te * 4u;
    const unsigned to4 = (unsigned)to * 4u;

    const float* base = lp + (size_t)n * CC;   // SGPR base for asm loads

#define GLOAD(dst, off) asm volatile("global_load_dword %0, %1, %2" \
        : "=v"(dst) : "v"(off), "s"(base))

#define DECLP(d) float pb##d, p1##d, p2##d;
    DECLP(0)  DECLP(1)  DECLP(2)  DECLP(3)
    DECLP(4)  DECLP(5)  DECLP(6)  DECLP(7)
    DECLP(8)  DECLP(9)  DECLP(10) DECLP(11)
    DECLP(12) DECLP(13) DECLP(14) DECLP(15)

    unsigned vb = 0;   // rolling byte offset of next row to issue
#define PRO(d) { GLOAD(pb##d, vb); \
                 const unsigned x1 = vb + te4; GLOAD(p1##d, x1); \
                 const unsigned x2 = vb + to4; GLOAD(p2##d, x2); \
                 vb += STRB; }
    PRO(0)  PRO(1)  PRO(2)  PRO(3)
    PRO(4)  PRO(5)  PRO(6)  PRO(7)
    PRO(8)  PRO(9)  PRO(10) PRO(11)
    PRO(12) PRO(13) PRO(14) PRO(15)
    // 48 loads in flight; vb now at row 16.

    // scaled linear-domain state: stored = alpha_true * 2^kk (per-lane kk)
    float b0 = (lane == 0) ? 1.0f : 0.0f;
    float b1 = 0.0f, b2 = 0.0f, b3 = 0.0f, b4 = 0.0f;
    int kk = 0;

    // wait until slot d's 3 loads (oldest outstanding) retired; tie values
    // so no consumer can be scheduled above the wait.
#define WAITN(d, cnt) asm volatile("s_waitcnt vmcnt(" #cnt ")" \
        : "+v"(pb##d), "+v"(p1##d), "+v"(p2##d))

#define COMPUTE(eb, e1, e3) { \
    const float p3r = __shfl_up(b3, 1, 64); \
    const int   kpr = __shfl_up(kk, 1, 64); \
    const bool dorm = (fmaxf(fmaxf(b0, b1), fmaxf(b2, b3)) == 0.0f); \
    kk = dorm ? kpr : kk;                      /* adopt neighbor frame */ \
    int dkv = kk - kpr; \
    dkv = dkv < -126 ? -126 : (dkv > 126 ? 126 : dkv); \
    const float fac = __int_as_float((dkv + 127) << 23);  /* 2^dk exact */ \
    const float p3 = (lane == 0) ? 0.0f : p3r * fac; \
    const float n0 = eb * (b0 + p3); \
    const float n1 = e1 * (b1 + b0 + (skip1 ? p3 : 0.0f)); \
    const float n2 = eb * (b2 + b1); \
    const float n3 = e3 * (b3 + b2 + (skip3 ? b1 : 0.0f)); \
    const float n4 = eb * (b4 + b3); \
    b0 = n0; b1 = n1; b2 = n2; b3 = n3; b4 = n4; }

    // exact power-of-2 renorm to max~1; kk absorbs the exponent.
    // stored' = stored * 2^(127-e8)  =>  kk += 127 - e8  (round-5 fix)
#define RESCALE { \
    const float m = fmaxf(fmaxf(fmaxf(b0, b1), fmaxf(b2, b3)), b4); \
    int e8 = (__float_as_int(m) >> 23) & 255; \
    e8 = e8 > 253 ? 253 : e8; \
    const float sc = __int_as_float((254 - e8) << 23);   /* 2^(127-e8) */ \
    b0 *= sc; b1 *= sc; b2 *= sc; b3 *= sc; b4 *= sc; \
    kk += 127 - e8; }

#define STEPM(d) { \
    WAITN(d, 45); \
    const float eb = __builtin_amdgcn_exp2f(pb##d * LOG2E); \
    const float e1 = __builtin_amdgcn_exp2f(p1##d * LOG2E); \
    const float e3 = __builtin_amdgcn_exp2f(p2##d * LOG2E); \
    { const unsigned vc = (vb < CAPB) ? vb : CAPB; \
      GLOAD(pb##d, vc); \
      const unsigned x1 = vc + te4; GLOAD(p1##d, x1); \
      const unsigned x2 = vc + to4; GLOAD(p2##d, x2); \
      vb += STRB; } \
    COMPUTE(eb, e1, e3) }

    int t0 = 0;
    for (; t0 + 16 <= ilen; t0 += 16) {
        STEPM(0)  STEPM(1)  STEPM(2)  STEPM(3)
        STEPM(4)  STEPM(5)  STEPM(6)  STEPM(7)
        RESCALE
        STEPM(8)  STEPM(9)  STEPM(10) STEPM(11)
        STEPM(12) STEPM(13) STEPM(14) STEPM(15)
        RESCALE
    }

    // tail: consume remaining slots (rows t0+d), no reissue; counted waits.
#define TAILS(d, cnt) if (t0 + (d) < ilen) { \
    WAITN(d, cnt); \
    const float eb = __builtin_amdgcn_exp2f(pb##d * LOG2E); \
    const float e1 = __builtin_amdgcn_exp2f(p1##d * LOG2E); \
    const float e3 = __builtin_amdgcn_exp2f(p2##d * LOG2E); \
    COMPUTE(eb, e1, e3) }

    TAILS(0, 45)  TAILS(1, 42)  TAILS(2, 39)  TAILS(3, 36)
    TAILS(4, 33)  TAILS(5, 30)  TAILS(6, 27)  TAILS(7, 24)
    RESCALE
    TAILS(8, 21)  TAILS(9, 18)  TAILS(10, 15) TAILS(11, 12)
    TAILS(12, 9)  TAILS(13, 6)  TAILS(14, 3)  TAILS(15, 0)

    asm volatile("s_waitcnt vmcnt(0)" ::: "memory");  // drain before endpgm

    // epilogue: per-position log2(alpha_true) = log2(stored) - kk
    const float kf = (float)kk;
    alds[4 * lane + 0] = __builtin_amdgcn_logf(b0) - kf;
    alds[4 * lane + 1] = __builtin_amdgcn_logf(b1) - kf;
    alds[4 * lane + 2] = __builtin_amdgcn_logf(b2) - kf;
    alds[4 * lane + 3] = __builtin_amdgcn_logf(b3) - kf;
    if (lane == 63) alds[256] = __builtin_amdgcn_logf(b4) - kf;
    __syncthreads();
    if (lane == 0) {
        const int idx = 2 * tlen;
        const float r = lae2(alds[idx], alds[idx - 1]);  // log2 domain
        ws[n] = -(r * LN2) / (float)tlen;
    }
}

__global__ __launch_bounds__(64) void ctc_reduce_kernel(
    const float* __restrict__ ws, float* __restrict__ out)
{
    const int lane = threadIdx.x;
    float s = ws[lane] + ws[lane + 64] + ws[lane + 128] + ws[lane + 192];
    #pragma unroll
    for (int off = 32; off > 0; off >>= 1)
        s += __shfl_down(s, off, 64);
    if (lane == 0) out[0] = s * (1.0f / NN);
}

extern "C" void kernel_launch(void* const* d_in, const int* in_sizes, int n_in,
                              void* d_out, int out_size, void* d_ws, size_t ws_size,
                              hipStream_t stream) {
    const float* lp  = (const float*)d_in[0];   // (T, N, C) f32
    const int*   tgt = (const int*)d_in[1];     // (N, S) i32
    const int*   il  = (const int*)d_in[2];     // (N,) i32
    const int*   tl  = (const int*)d_in[3];     // (N,) i32
    float* out = (float*)d_out;
    float* ws  = (float*)d_ws;

    hipLaunchKernelGGL(ctc_alpha_kernel, dim3(NN), dim3(64), 0, stream,
                       lp, tgt, il, tl, ws);
    hipLaunchKernelGGL(ctc_reduce_kernel, dim3(1), dim3(64), 0, stream, ws, out);
}

// Round 8
// 238.855 us; speedup vs baseline: 2.0624x; 1.0484x over previous
//
#include <hip/hip_runtime.h>

#define TT 1024
#define NN 256
#define CC 128
#define SS 128
#define STRB 131072u                  // NN*CC*4 bytes per time-row
#define CAPB (1023u * STRB)           // last valid row offset
#define LOG2E 1.4426950408889634f
#define LN2 0.6931471805599453f

// log2(2^a + 2^b) for the tiny epilogue only
__device__ __forceinline__ float lae2(float a, float b) {
    float m = fmaxf(a, b);
    float mn = fminf(a, b);
    float s = 1.0f + __builtin_amdgcn_exp2f(mn - m);
    return m + __builtin_amdgcn_logf(s);   // v_log_f32 is log2
}

// DPP wave_shr:1 (ctrl 0x138): lane i receives lane i-1's value at VALU
// latency — no LDS round trip. Lane 0 receives `oldv`.
// ROUND-6 LESSON: __shfl_up is a ds_bpermute (~120 cy latency, m117) and
// sits on a 1-step serial recurrence (kk -> shfl -> kk), pinning the step
// at ~246 cy. DPP removes the LDS round trip from the critical path.
__device__ __forceinline__ float dpp_shr1_f(float x, float oldv) {
    int r = __builtin_amdgcn_update_dpp(__float_as_int(oldv), __float_as_int(x),
                                        0x138, 0xf, 0xf, false);
    return __int_as_float(r);
}
__device__ __forceinline__ int dpp_shr1_i(int x, int oldv) {
    return __builtin_amdgcn_update_dpp(oldv, x, 0x138, 0xf, 0xf, false);
}

// One wave per sample. Lane i owns extended positions l=4i..4i+3 (b0..b3);
// b4 is l=4i+4 (only lane 63's, l=256, is ever read).
// Volatile-asm global loads (can't be sunk) + counted s_waitcnt vmcnt(45)
// tying consumers as "+v" (hard dataflow edge). Linear-domain probabilities,
// per-lane exact power-of-2 scale frame kk (stored = alpha_true * 2^kk),
// rescale every 8 steps (kk += 127 - e8; round-5 sign fix).
__global__ __launch_bounds__(64, 1) void ctc_alpha_kernel(
    const float* __restrict__ lp, const int* __restrict__ tgt,
    const int* __restrict__ ilen_p, const int* __restrict__ tlen_p,
    float* __restrict__ ws)
{
    __shared__ float alds[260];

    const int n = blockIdx.x;
    const int lane = threadIdx.x;
    const int ilen = ilen_p[n];      // [512, 1024]
    const int tlen = tlen_p[n];      // [64, 128]

    const int te = tgt[n * SS + 2 * lane]     & (CC - 1);  // ext[4i+1]
    const int to = tgt[n * SS + 2 * lane + 1] & (CC - 1);  // ext[4i+3]
    const int tprev = __shfl_up(to, 1, 64);                // init only
    const bool skip1 = (lane > 0) && (te != tprev);
    const bool skip3 = (to != te);
    const unsigned te4 = (unsigned)te * 4u;
    const unsigned to4 = (unsigned)to * 4u;

    const float* base = lp + (size_t)n * CC;   // SGPR base for asm loads

#define GLOAD(dst, off) asm volatile("global_load_dword %0, %1, %2" \
        : "=v"(dst) : "v"(off), "s"(base))

#define DECLP(d) float pb##d, p1##d, p2##d;
    DECLP(0)  DECLP(1)  DECLP(2)  DECLP(3)
    DECLP(4)  DECLP(5)  DECLP(6)  DECLP(7)
    DECLP(8)  DECLP(9)  DECLP(10) DECLP(11)
    DECLP(12) DECLP(13) DECLP(14) DECLP(15)

    unsigned vb = 0;   // rolling byte offset of next row to issue
#define PRO(d) { GLOAD(pb##d, vb); \
                 const unsigned x1 = vb + te4; GLOAD(p1##d, x1); \
                 const unsigned x2 = vb + to4; GLOAD(p2##d, x2); \
                 vb += STRB; }
    PRO(0)  PRO(1)  PRO(2)  PRO(3)
    PRO(4)  PRO(5)  PRO(6)  PRO(7)
    PRO(8)  PRO(9)  PRO(10) PRO(11)
    PRO(12) PRO(13) PRO(14) PRO(15)
    // 48 loads in flight (vmcnt max 63); vb now at row 16.

    // scaled linear-domain state: stored = alpha_true * 2^kk (per-lane kk)
    float b0 = (lane == 0) ? 1.0f : 0.0f;
    float b1 = 0.0f, b2 = 0.0f, b3 = 0.0f, b4 = 0.0f;
    int kk = 0;

#define WAITN(d, cnt) asm volatile("s_waitcnt vmcnt(" #cnt ")" \
        : "+v"(pb##d), "+v"(p1##d), "+v"(p2##d))

    // DPP gives lane i-1's value at VALU speed; lane 0 gets oldv.
    // p3 conversion: true = p3r*2^-kpr; own frame: *2^kk -> ldexp(p3r, kk-kpr).
    // No clamp needed: |kk-kpr| large only when the left lane is dormant,
    // and then p3r == 0 (ldexp(0, x) == 0).
#define COMPUTE(eb, e1, e3) { \
    const float p3r = dpp_shr1_f(b3, 0.0f); \
    const int   kpr = dpp_shr1_i(kk, kk); \
    const bool dorm = (fmaxf(fmaxf(b0, b1), fmaxf(b2, b3)) == 0.0f); \
    kk = dorm ? kpr : kk;                      /* adopt neighbor frame */ \
    const float p3 = ldexpf(p3r, kk - kpr); \
    const float n0 = eb * (b0 + p3); \
    const float n1 = e1 * (b1 + b0 + (skip1 ? p3 : 0.0f)); \
    const float n2 = eb * (b2 + b1); \
    const float n3 = e3 * (b3 + b2 + (skip3 ? b1 : 0.0f)); \
    const float n4 = eb * (b4 + b3); \
    b0 = n0; b1 = n1; b2 = n2; b3 = n3; b4 = n4; }

    // exact power-of-2 renorm to max~1; kk absorbs the exponent.
#define RESCALE { \
    const float m = fmaxf(fmaxf(fmaxf(b0, b1), fmaxf(b2, b3)), b4); \
    int e8 = (__float_as_int(m) >> 23) & 255; \
    e8 = e8 > 253 ? 253 : e8; \
    const float sc = __int_as_float((254 - e8) << 23);   /* 2^(127-e8) */ \
    b0 *= sc; b1 *= sc; b2 *= sc; b3 *= sc; b4 *= sc; \
    kk += 127 - e8; }

#define STEPM(d) { \
    WAITN(d, 45); \
    const float eb = __builtin_amdgcn_exp2f(pb##d * LOG2E); \
    const float e1 = __builtin_amdgcn_exp2f(p1##d * LOG2E); \
    const float e3 = __builtin_amdgcn_exp2f(p2##d * LOG2E); \
    { const unsigned vc = (vb < CAPB) ? vb : CAPB; \
      GLOAD(pb##d, vc); \
      const unsigned x1 = vc + te4; GLOAD(p1##d, x1); \
      const unsigned x2 = vc + to4; GLOAD(p2##d, x2); \
      vb += STRB; } \
    COMPUTE(eb, e1, e3) }

    int t0 = 0;
    for (; t0 + 16 <= ilen; t0 += 16) {
        STEPM(0)  STEPM(1)  STEPM(2)  STEPM(3)
        STEPM(4)  STEPM(5)  STEPM(6)  STEPM(7)
        RESCALE
        STEPM(8)  STEPM(9)  STEPM(10) STEPM(11)
        STEPM(12) STEPM(13) STEPM(14) STEPM(15)
        RESCALE
    }

    // tail: consume remaining slots (rows t0+d), no reissue; counted waits.
#define TAILS(d, cnt) if (t0 + (d) < ilen) { \
    WAITN(d, cnt); \
    const float eb = __builtin_amdgcn_exp2f(pb##d * LOG2E); \
    const float e1 = __builtin_amdgcn_exp2f(p1##d * LOG2E); \
    const float e3 = __builtin_amdgcn_exp2f(p2##d * LOG2E); \
    COMPUTE(eb, e1, e3) }

    TAILS(0, 45)  TAILS(1, 42)  TAILS(2, 39)  TAILS(3, 36)
    TAILS(4, 33)  TAILS(5, 30)  TAILS(6, 27)  TAILS(7, 24)
    RESCALE
    TAILS(8, 21)  TAILS(9, 18)  TAILS(10, 15) TAILS(11, 12)
    TAILS(12, 9)  TAILS(13, 6)  TAILS(14, 3)  TAILS(15, 0)

    asm volatile("s_waitcnt vmcnt(0)" ::: "memory");  // drain before endpgm

    // epilogue: per-position log2(alpha_true) = log2(stored) - kk
    const float kf = (float)kk;
    alds[4 * lane + 0] = __builtin_amdgcn_logf(b0) - kf;
    alds[4 * lane + 1] = __builtin_amdgcn_logf(b1) - kf;
    alds[4 * lane + 2] = __builtin_amdgcn_logf(b2) - kf;
    alds[4 * lane + 3] = __builtin_amdgcn_logf(b3) - kf;
    if (lane == 63) alds[256] = __builtin_amdgcn_logf(b4) - kf;
    __syncthreads();
    if (lane == 0) {
        const int idx = 2 * tlen;
        const float r = lae2(alds[idx], alds[idx - 1]);  // log2 domain
        ws[n] = -(r * LN2) / (float)tlen;
    }
}

__global__ __launch_bounds__(64) void ctc_reduce_kernel(
    const float* __restrict__ ws, float* __restrict__ out)
{
    const int lane = threadIdx.x;
    float s = ws[lane] + ws[lane + 64] + ws[lane + 128] + ws[lane + 192];
    #pragma unroll
    for (int off = 32; off > 0; off >>= 1)
        s += __shfl_down(s, off, 64);
    if (lane == 0) out[0] = s * (1.0f / NN);
}

extern "C" void kernel_launch(void* const* d_in, const int* in_sizes, int n_in,
                              void* d_out, int out_size, void* d_ws, size_t ws_size,
                              hipStream_t stream) {
    const float* lp  = (const float*)d_in[0];   // (T, N, C) f32
    const int*   tgt = (const int*)d_in[1];     // (N, S) i32
    const int*   il  = (const int*)d_in[2];     // (N,) i32
    const int*   tl  = (const int*)d_in[3];     // (N,) i32
    float* out = (float*)d_out;
    float* ws  = (float*)d_ws;

    hipLaunchKernelGGL(ctc_alpha_kernel, dim3(NN), dim3(64), 0, stream,
                       lp, tgt, il, tl, ws);
    hipLaunchKernelGGL(ctc_reduce_kernel, dim3(1), dim3(64), 0, stream, ws, out);
}

// Round 9
// 225.560 us; speedup vs baseline: 2.1839x; 1.0589x over previous
//
#include <hip/hip_runtime.h>

#define TT 1024
#define NN 256
#define CC 128
#define SS 128
#define STRB 131072u                  // NN*CC*4 bytes per time-row
#define CAPB (1023u * STRB)           // last valid row offset
#define LOG2E 1.4426950408889634f
#define LN2 0.6931471805599453f

// log2(2^a + 2^b) for the tiny epilogue only
__device__ __forceinline__ float lae2(float a, float b) {
    float m = fmaxf(a, b);
    float mn = fminf(a, b);
    float s = 1.0f + __builtin_amdgcn_exp2f(mn - m);
    return m + __builtin_amdgcn_logf(s);   // v_log_f32 is log2
}

// DPP wave_shr:1 (ctrl 0x138): lane i receives lane i-1's value at VALU
// latency. Lane 0 receives `oldv`.
__device__ __forceinline__ float dpp_shr1_f(float x, float oldv) {
    int r = __builtin_amdgcn_update_dpp(__float_as_int(oldv), __float_as_int(x),
                                        0x138, 0xf, 0xf, false);
    return __int_as_float(r);
}
__device__ __forceinline__ int dpp_shr1_i(int x, int oldv) {
    return __builtin_amdgcn_update_dpp(oldv, x, 0x138, 0xf, 0xf, false);
}

// One wave per sample. Lane i owns extended positions l=4i..4i+3 (b0..b3);
// b4 is l=4i+4 (only lane 63's, l=256, is ever read).
// Volatile-asm global loads (can't be sunk) + counted s_waitcnt vmcnt(45)
// tying consumers as "+v" (hard dataflow edge). Linear-domain probabilities,
// per-lane exact power-of-2 scale frame kk (stored = alpha_true * 2^kk).
//
// ROUND-8 LESSON: per-step cost 224 cy = ~105 issue + ~119 stall; the kk
// frame machinery (dorm fmax-chain + cndmask + sub + ldexp) sat on the
// serial path every step. kk is CONSTANT between rescales -> hoist all
// frame logic (adoption + conversion factor fac = 2^(kk-kpr)) into the
// 8-step window boundary. Per-step: p3 = dpp(b3)*fac only.
__global__ __launch_bounds__(64, 1) void ctc_alpha_kernel(
    const float* __restrict__ lp, const int* __restrict__ tgt,
    const int* __restrict__ ilen_p, const int* __restrict__ tlen_p,
    float* __restrict__ ws)
{
    __shared__ float alds[260];

    const int n = blockIdx.x;
    const int lane = threadIdx.x;
    const int ilen = ilen_p[n];      // [512, 1024]
    const int tlen = tlen_p[n];      // [64, 128]

    const int te = tgt[n * SS + 2 * lane]     & (CC - 1);  // ext[4i+1]
    const int to = tgt[n * SS + 2 * lane + 1] & (CC - 1);  // ext[4i+3]
    const int tprev = __shfl_up(to, 1, 64);                // init only
    const bool skip1 = (lane > 0) && (te != tprev);
    const bool skip3 = (to != te);
    const unsigned te4 = (unsigned)te * 4u;
    const unsigned to4 = (unsigned)to * 4u;

    const float* base = lp + (size_t)n * CC;   // SGPR base for asm loads

#define GLOAD(dst, off) asm volatile("global_load_dword %0, %1, %2" \
        : "=v"(dst) : "v"(off), "s"(base))

#define DECLP(d) float pb##d, p1##d, p2##d;
    DECLP(0)  DECLP(1)  DECLP(2)  DECLP(3)
    DECLP(4)  DECLP(5)  DECLP(6)  DECLP(7)
    DECLP(8)  DECLP(9)  DECLP(10) DECLP(11)
    DECLP(12) DECLP(13) DECLP(14) DECLP(15)

    unsigned vb = 0;   // rolling byte offset of next row to issue
#define PRO(d) { GLOAD(pb##d, vb); \
                 const unsigned x1 = vb + te4; GLOAD(p1##d, x1); \
                 const unsigned x2 = vb + to4; GLOAD(p2##d, x2); \
                 vb += STRB; }
    PRO(0)  PRO(1)  PRO(2)  PRO(3)
    PRO(4)  PRO(5)  PRO(6)  PRO(7)
    PRO(8)  PRO(9)  PRO(10) PRO(11)
    PRO(12) PRO(13) PRO(14) PRO(15)
    // 48 loads in flight (vmcnt max 63); vb now at row 16.

    // scaled linear-domain state: stored = alpha_true * 2^kk (per-lane kk)
    float b0 = (lane == 0) ? 1.0f : 0.0f;
    float b1 = 0.0f, b2 = 0.0f, b3 = 0.0f, b4 = 0.0f;
    int kk = 0;
    float fac = 1.0f;   // 2^(kk - kk_left), loop-invariant within a window

#define WAITN(d, cnt) asm volatile("s_waitcnt vmcnt(" #cnt ")" \
        : "+v"(pb##d), "+v"(p1##d), "+v"(p2##d))

    // Per-step: one DPP + one mul for the cross-lane term; no frame logic.
#define COMPUTE(eb, e1, e3) { \
    const float p3 = dpp_shr1_f(b3, 0.0f) * fac; \
    const float n0 = eb * (b0 + p3); \
    const float n1 = e1 * (b1 + b0 + (skip1 ? p3 : 0.0f)); \
    const float n2 = eb * (b2 + b1); \
    const float n3 = e3 * (b3 + b2 + (skip3 ? b1 : 0.0f)); \
    const float n4 = eb * (b4 + b3); \
    b0 = n0; b1 = n1; b2 = n2; b3 = n3; b4 = n4; }

    // Window boundary (every 8 steps): rescale active lanes to max~1,
    // dormant lanes adopt the nearest active frame to the left (5-hop DPP
    // propagation: front advances <=4 lanes per window), rebuild fac.
    // dk clamp +-96: growth bound (e<=1 -> <=x3/step) keeps p3 < 2^122.
#define WINBND { \
    const float m = fmaxf(fmaxf(fmaxf(b0, b1), fmaxf(b2, b3)), b4); \
    const bool act = (m > 0.0f); \
    int e8 = (__float_as_int(m) >> 23) & 255; \
    e8 = e8 > 253 ? 253 : e8; \
    const float sc = __int_as_float((254 - e8) << 23);   /* 2^(127-e8) */ \
    b0 *= sc; b1 *= sc; b2 *= sc; b3 *= sc; b4 *= sc; \
    kk = act ? (kk + 127 - e8) : kk; \
    int kn; \
    kn = dpp_shr1_i(kk, kk); kk = act ? kk : kn; \
    kn = dpp_shr1_i(kk, kk); kk = act ? kk : kn; \
    kn = dpp_shr1_i(kk, kk); kk = act ? kk : kn; \
    kn = dpp_shr1_i(kk, kk); kk = act ? kk : kn; \
    kn = dpp_shr1_i(kk, kk); kk = act ? kk : kn; \
    const int kpr2 = dpp_shr1_i(kk, kk); \
    int dk = kk - kpr2; \
    dk = dk < -96 ? -96 : (dk > 96 ? 96 : dk); \
    fac = __int_as_float((dk + 127) << 23); \
}

#define STEPM(d) { \
    WAITN(d, 45); \
    const float eb = __builtin_amdgcn_exp2f(pb##d * LOG2E); \
    const float e1 = __builtin_amdgcn_exp2f(p1##d * LOG2E); \
    const float e3 = __builtin_amdgcn_exp2f(p2##d * LOG2E); \
    { const unsigned vc = (vb < CAPB) ? vb : CAPB; \
      GLOAD(pb##d, vc); \
      const unsigned x1 = vc + te4; GLOAD(p1##d, x1); \
      const unsigned x2 = vc + to4; GLOAD(p2##d, x2); \
      vb += STRB; } \
    COMPUTE(eb, e1, e3) }

    int t0 = 0;
    for (; t0 + 16 <= ilen; t0 += 16) {
        STEPM(0)  STEPM(1)  STEPM(2)  STEPM(3)
        STEPM(4)  STEPM(5)  STEPM(6)  STEPM(7)
        WINBND
        STEPM(8)  STEPM(9)  STEPM(10) STEPM(11)
        STEPM(12) STEPM(13) STEPM(14) STEPM(15)
        WINBND
    }

    // tail: consume remaining slots (rows t0+d), no reissue; counted waits.
#define TAILS(d, cnt) if (t0 + (d) < ilen) { \
    WAITN(d, cnt); \
    const float eb = __builtin_amdgcn_exp2f(pb##d * LOG2E); \
    const float e1 = __builtin_amdgcn_exp2f(p1##d * LOG2E); \
    const float e3 = __builtin_amdgcn_exp2f(p2##d * LOG2E); \
    COMPUTE(eb, e1, e3) }

    TAILS(0, 45)  TAILS(1, 42)  TAILS(2, 39)  TAILS(3, 36)
    TAILS(4, 33)  TAILS(5, 30)  TAILS(6, 27)  TAILS(7, 24)
    WINBND
    TAILS(8, 21)  TAILS(9, 18)  TAILS(10, 15) TAILS(11, 12)
    TAILS(12, 9)  TAILS(13, 6)  TAILS(14, 3)  TAILS(15, 0)

    asm volatile("s_waitcnt vmcnt(0)" ::: "memory");  // drain before endpgm

    // epilogue: per-position log2(alpha_true) = log2(stored) - kk
    const float kf = (float)kk;
    alds[4 * lane + 0] = __builtin_amdgcn_logf(b0) - kf;
    alds[4 * lane + 1] = __builtin_amdgcn_logf(b1) - kf;
    alds[4 * lane + 2] = __builtin_amdgcn_logf(b2) - kf;
    alds[4 * lane + 3] = __builtin_amdgcn_logf(b3) - kf;
    if (lane == 63) alds[256] = __builtin_amdgcn_logf(b4) - kf;
    __syncthreads();
    if (lane == 0) {
        const int idx = 2 * tlen;
        const float r = lae2(alds[idx], alds[idx - 1]);  // log2 domain
        ws[n] = -(r * LN2) / (float)tlen;
    }
}

__global__ __launch_bounds__(64) void ctc_reduce_kernel(
    const float* __restrict__ ws, float* __restrict__ out)
{
    const int lane = threadIdx.x;
    float s = ws[lane] + ws[lane + 64] + ws[lane + 128] + ws[lane + 192];
    #pragma unroll
    for (int off = 32; off > 0; off >>= 1)
        s += __shfl_down(s, off, 64);
    if (lane == 0) out[0] = s * (1.0f / NN);
}

extern "C" void kernel_launch(void* const* d_in, const int* in_sizes, int n_in,
                              void* d_out, int out_size, void* d_ws, size_t ws_size,
                              hipStream_t stream) {
    const float* lp  = (const float*)d_in[0];   // (T, N, C) f32
    const int*   tgt = (const int*)d_in[1];     // (N, S) i32
    const int*   il  = (const int*)d_in[2];     // (N,) i32
    const int*   tl  = (const int*)d_in[3];     // (N,) i32
    float* out = (float*)d_out;
    float* ws  = (float*)d_ws;

    hipLaunchKernelGGL(ctc_alpha_kernel, dim3(NN), dim3(64), 0, stream,
                       lp, tgt, il, tl, ws);
    hipLaunchKernelGGL(ctc_reduce_kernel, dim3(1), dim3(64), 0, stream, ws, out);
}